// Round 1
// baseline (338.525 us; speedup 1.0000x reference)
//
#include <hip/hip_runtime.h>
#include <hip/hip_bf16.h>

typedef __attribute__((ext_vector_type(8))) short short8;
typedef __attribute__((ext_vector_type(4))) float f32x4;

struct alignas(8) US4 { unsigned short x, y, z, w; };

// ---------------- ndtri in double (Acklam + 2 Halley refinements) ----------------
__device__ double ndtri_d(double p) {
    const double a1 = -3.969683028665376e+01, a2 = 2.209460984245205e+02,
                 a3 = -2.759285104469687e+02, a4 = 1.383577518672690e+02,
                 a5 = -3.066479806614716e+01, a6 = 2.506628277459239e+00;
    const double b1 = -5.447609879822406e+01, b2 = 1.615858368580409e+02,
                 b3 = -1.556989798598866e+02, b4 = 6.680131188771972e+01,
                 b5 = -1.328068155288572e+01;
    const double c1 = -7.784894002430293e-03, c2 = -3.223964580411365e-01,
                 c3 = -2.400758277161838e+00, c4 = -2.549732539343734e+00,
                 c5 = 4.374664141464968e+00,  c6 = 2.938163982698783e+00;
    const double d1 = 7.784695709041462e-03, d2 = 3.224671290700398e-01,
                 d3 = 2.445134137142996e+00, d4 = 3.754408661907416e+00;
    const double plow = 0.02425, phigh = 1.0 - 0.02425;
    double x;
    if (p < plow) {
        double q = sqrt(-2.0 * log(p));
        x = (((((c1*q+c2)*q+c3)*q+c4)*q+c5)*q+c6) / ((((d1*q+d2)*q+d3)*q+d4)*q+1.0);
    } else if (p <= phigh) {
        double q = p - 0.5, r = q * q;
        x = (((((a1*r+a2)*r+a3)*r+a4)*r+a5)*r+a6)*q / (((((b1*r+b2)*r+b3)*r+b4)*r+b5)*r+1.0);
    } else {
        double q = sqrt(-2.0 * log(1.0 - p));
        x = -(((((c1*q+c2)*q+c3)*q+c4)*q+c5)*q+c6) / ((((d1*q+d2)*q+d3)*q+d4)*q+1.0);
    }
    // Halley refinement via erfc-based normal CDF: brings error to ~1e-15.
    #pragma unroll
    for (int it = 0; it < 2; ++it) {
        double e = 0.5 * erfc(-x * 0.70710678118654752440) - p;
        double u = e * 2.50662827463100050242 * exp(0.5 * x * x);
        x = x - u / (1.0 + 0.5 * x * u);
    }
    return x;
}

// table[32], bounds[32] (bounds[31] = +inf sentinel)
__global__ void build_table_k(float* __restrict__ table, float* __restrict__ bounds) {
    __shared__ float sT[32];
    const int i = threadIdx.x;  // 0..31
    const double OFF = 0.9677083;
    double v;
    if (i == 16) {
        v = 0.0;
    } else if (i < 16) {
        const double a = 1.0 - OFF;
        double p = a + (0.5 - a) * ((double)i / 16.0);
        v = ndtri_d(p) / (-ndtri_d(a));        // neg / (-neg[0])
    } else {
        int j = i - 16;                        // 1..15
        double p = 0.5 + (OFF - 0.5) * ((double)j / 15.0);
        v = ndtri_d(p) / ndtri_d(OFF);         // pos / pos[-1]
    }
    float tv = (float)v;
    sT[i] = tv;
    table[i] = tv;
    __syncthreads();
    if (i < 31) bounds[i] = 0.5f * (sT[i] + sT[i + 1]);  // fp32, like reference
    else        bounds[31] = __builtin_inff();
}

// ---------------- blockwise NF5 quantize: fp32 -> bf16 ----------------
// One thread = 4 consecutive elements; 8 lanes = one 32-element block.
__device__ __forceinline__ unsigned short q_one(float n, const float* sT,
                                                const float* sB, float scale) {
    // idx = count of boundaries < n   (searchsorted side='left')
    int idx = (sB[15] < n) ? 16 : 0;
    idx += (sB[idx + 7] < n) ? 8 : 0;
    idx += (sB[idx + 3] < n) ? 4 : 0;
    idx += (sB[idx + 1] < n) ? 2 : 0;
    idx += (sB[idx]     < n) ? 1 : 0;
    float q = sT[idx] * scale;                 // exact fp32 (pow2 scale)
    __hip_bfloat16 h = __float2bfloat16(q);
    return *reinterpret_cast<unsigned short*>(&h);
}

__global__ __launch_bounds__(256) void quantize_k(const float4* __restrict__ in,
                                                  US4* __restrict__ out,
                                                  const float* __restrict__ table,
                                                  const float* __restrict__ bounds,
                                                  int n4) {
    __shared__ float sT[32], sB[32];
    const int tid = threadIdx.x;
    if (tid < 32) { sT[tid] = table[tid]; sB[tid] = bounds[tid]; }
    __syncthreads();
    const int t = blockIdx.x * 256 + tid;
    if (t >= n4) return;
    float4 v = in[t];
    float am = fmaxf(fmaxf(fabsf(v.x), fabsf(v.y)), fmaxf(fabsf(v.z), fabsf(v.w)));
    // reduce amax over the 8-lane group (32-element block)
    am = fmaxf(am, __shfl_xor(am, 1));
    am = fmaxf(am, __shfl_xor(am, 2));
    am = fmaxf(am, __shfl_xor(am, 4));
    am = fmaxf(am, 1e-12f);
    // scale = exp2(ceil(log2(am))) exactly: smallest power of 2 >= am
    int e;
    float m = frexpf(am, &e);                  // am = m * 2^e, m in [0.5, 1)
    int se = (m == 0.5f) ? (e - 1) : e;
    float scale = ldexpf(1.0f, se);
    float inv   = ldexpf(1.0f, -se);           // exact reciprocal
    US4 o;
    o.x = q_one(v.x * inv, sT, sB, scale);
    o.y = q_one(v.y * inv, sT, sB, scale);
    o.z = q_one(v.z * inv, sT, sB, scale);
    o.w = q_one(v.w * inv, sT, sB, scale);
    out[t] = o;
}

// ---------------- bf16 MFMA GEMM, C[M,N] = A[M,K] * B[N,K]^T + bias ----------------
__device__ __forceinline__ void gload_lds16(const unsigned short* g, unsigned short* s) {
    __builtin_amdgcn_global_load_lds(
        (const __attribute__((address_space(1))) unsigned int*)g,
        (__attribute__((address_space(3))) unsigned int*)s, 16, 0, 0);
}

__global__ __launch_bounds__(256) void gemm_bt_k(const unsigned short* __restrict__ A,
                                                 const unsigned short* __restrict__ B,
                                                 const float* __restrict__ bias,
                                                 float* __restrict__ C,
                                                 int M, int N, int K) {
    __shared__ unsigned short sA[128 * 64];
    __shared__ unsigned short sB[128 * 64];
    const int t = threadIdx.x;
    const int w = t >> 6, l = t & 63;
    const int m_blk = blockIdx.y * 128, n_blk = blockIdx.x * 128;
    const int wm = (w >> 1) * 64, wn = (w & 1) * 64;   // wave's 64x64 quadrant

    f32x4 acc[4][4];
    #pragma unroll
    for (int i = 0; i < 4; ++i)
        #pragma unroll
        for (int j = 0; j < 4; ++j)
            acc[i][j] = (f32x4){0.f, 0.f, 0.f, 0.f};

    const int st_row = (l >> 3);        // 0..7 within an 8-row chunk
    const int st_col = (l & 7) * 8;     // 0..56, 8 halves each

    for (int kt = 0; kt < K; kt += 64) {
        __syncthreads();
        #pragma unroll
        for (int j = 0; j < 4; ++j) {
            const int chunk = w * 4 + j;             // 0..15 -> rows chunk*8..+7
            const int row = chunk * 8 + st_row;      // 0..127
            const unsigned short* ga = A + (size_t)(m_blk + row) * K + kt + st_col;
            const unsigned short* gb = B + (size_t)(n_blk + row) * K + kt + st_col;
            gload_lds16(ga, &sA[chunk * 512]);       // wave-uniform LDS base + lane*16B
            gload_lds16(gb, &sB[chunk * 512]);
        }
        __syncthreads();
        #pragma unroll
        for (int ks = 0; ks < 2; ++ks) {
            const int kof = ks * 32 + (l >> 4) * 8;  // A[m=l&15][k=quad*8+j] layout
            const int rsel = l & 15;
            short8 a[4], b[4];
            #pragma unroll
            for (int i = 0; i < 4; ++i) {
                a[i] = *(const short8*)&sA[(wm + i * 16 + rsel) * 64 + kof];
                b[i] = *(const short8*)&sB[(wn + i * 16 + rsel) * 64 + kof];
            }
            #pragma unroll
            for (int i = 0; i < 4; ++i)
                #pragma unroll
                for (int j = 0; j < 4; ++j)
                    acc[i][j] = __builtin_amdgcn_mfma_f32_16x16x32_bf16(
                        a[i], b[j], acc[i][j], 0, 0, 0);
        }
    }

    // epilogue: C/D layout col = l&15, row = (l>>4)*4 + r
    float bv[4];
    #pragma unroll
    for (int j = 0; j < 4; ++j) bv[j] = bias[n_blk + wn + j * 16 + (l & 15)];
    #pragma unroll
    for (int i = 0; i < 4; ++i) {
        #pragma unroll
        for (int r = 0; r < 4; ++r) {
            const int row = m_blk + wm + i * 16 + (l >> 4) * 4 + r;
            float* cp = C + (size_t)row * N + n_blk + wn + (l & 15);
            #pragma unroll
            for (int j = 0; j < 4; ++j)
                cp[j * 16] = acc[i][j][r] + bv[j];
        }
    }
}

extern "C" void kernel_launch(void* const* d_in, const int* in_sizes, int n_in,
                              void* d_out, int out_size, void* d_ws, size_t ws_size,
                              hipStream_t stream) {
    const float* x    = (const float*)d_in[0];
    const float* wgt  = (const float*)d_in[1];
    const float* bias = (const float*)d_in[2];
    float* out = (float*)d_out;

    const int x_size = in_sizes[0];      // 33554432
    const int w_size = in_sizes[1];      // 1048576
    const int N = in_sizes[2];           // 1024 (Dout)
    const int K = w_size / N;            // 1024 (Din)
    const int M = x_size / K;            // 32768

    char* ws = (char*)d_ws;
    unsigned short* qx = (unsigned short*)ws;
    unsigned short* qw = (unsigned short*)(ws + (size_t)M * K * sizeof(unsigned short));
    float* table  = (float*)(ws + (size_t)M * K * 2 + (size_t)N * K * 2);
    float* bounds = table + 32;

    build_table_k<<<1, 32, 0, stream>>>(table, bounds);

    const int n4x = x_size / 4;
    quantize_k<<<(n4x + 255) / 256, 256, 0, stream>>>(
        (const float4*)x, (US4*)qx, table, bounds, n4x);
    const int n4w = w_size / 4;
    quantize_k<<<(n4w + 255) / 256, 256, 0, stream>>>(
        (const float4*)wgt, (US4*)qw, table, bounds, n4w);

    dim3 grid(N / 128, M / 128);   // (8, 256)
    gemm_bt_k<<<grid, 256, 0, stream>>>(qx, qw, bias, out, M, N, K);
}

// Round 2
// 334.690 us; speedup vs baseline: 1.0115x; 1.0115x over previous
//
#include <hip/hip_runtime.h>
#include <hip/hip_bf16.h>

typedef __attribute__((ext_vector_type(8))) short short8;
typedef __attribute__((ext_vector_type(4))) float f32x4;

struct alignas(16) US8 { unsigned short s[8]; };

// ---------------- ndtri in double (Acklam + 2 Halley refinements) ----------------
__device__ double ndtri_d(double p) {
    const double a1 = -3.969683028665376e+01, a2 = 2.209460984245205e+02,
                 a3 = -2.759285104469687e+02, a4 = 1.383577518672690e+02,
                 a5 = -3.066479806614716e+01, a6 = 2.506628277459239e+00;
    const double b1 = -5.447609879822406e+01, b2 = 1.615858368580409e+02,
                 b3 = -1.556989798598866e+02, b4 = 6.680131188771972e+01,
                 b5 = -1.328068155288572e+01;
    const double c1 = -7.784894002430293e-03, c2 = -3.223964580411365e-01,
                 c3 = -2.400758277161838e+00, c4 = -2.549732539343734e+00,
                 c5 = 4.374664141464968e+00,  c6 = 2.938163982698783e+00;
    const double d1 = 7.784695709041462e-03, d2 = 3.224671290700398e-01,
                 d3 = 2.445134137142996e+00, d4 = 3.754408661907416e+00;
    const double plow = 0.02425, phigh = 1.0 - 0.02425;
    double x;
    if (p < plow) {
        double q = sqrt(-2.0 * log(p));
        x = (((((c1*q+c2)*q+c3)*q+c4)*q+c5)*q+c6) / ((((d1*q+d2)*q+d3)*q+d4)*q+1.0);
    } else if (p <= phigh) {
        double q = p - 0.5, r = q * q;
        x = (((((a1*r+a2)*r+a3)*r+a4)*r+a5)*r+a6)*q / (((((b1*r+b2)*r+b3)*r+b4)*r+b5)*r+1.0);
    } else {
        double q = sqrt(-2.0 * log(1.0 - p));
        x = -(((((c1*q+c2)*q+c3)*q+c4)*q+c5)*q+c6) / ((((d1*q+d2)*q+d3)*q+d4)*q+1.0);
    }
    #pragma unroll
    for (int it = 0; it < 2; ++it) {
        double e = 0.5 * erfc(-x * 0.70710678118654752440) - p;
        double u = e * 2.50662827463100050242 * exp(0.5 * x * x);
        x = x - u / (1.0 + 0.5 * x * u);
    }
    return x;
}

// table[32], bounds[32] (bounds[31]=+inf), lut[256] bucket->base index
__global__ void build_table_k(float* __restrict__ table, float* __restrict__ bounds,
                              unsigned char* __restrict__ lut) {
    __shared__ float sT[32], sBd[32];
    const int i = threadIdx.x;  // 0..31
    const double OFF = 0.9677083;
    double v;
    if (i == 16) {
        v = 0.0;
    } else if (i < 16) {
        const double a = 1.0 - OFF;
        double p = a + (0.5 - a) * ((double)i / 16.0);
        v = ndtri_d(p) / (-ndtri_d(a));
    } else {
        int j = i - 16;
        double p = 0.5 + (OFF - 0.5) * ((double)j / 15.0);
        v = ndtri_d(p) / ndtri_d(OFF);
    }
    float tv = (float)v;
    sT[i] = tv;
    table[i] = tv;
    __syncthreads();
    float bd;
    if (i < 31) bd = 0.5f * (sT[i] + sT[i + 1]);   // fp32, like reference
    else        bd = __builtin_inff();
    sBd[i] = bd;
    bounds[i] = bd;
    __syncthreads();
    // LUT with margin 2^-20: base[j] = count(bounds < n_j - margin).
    // Bucket-rounding error of fp32 u is <= 2^-23 in n-units; margin absorbs it,
    // and min boundary gap (~0.035) >> 2*bucket width (0.0156) guarantees the
    // single-step fixup recovers exact searchsorted semantics.
    for (int j = i; j < 256; j += 32) {
        float nj = (float)j * (1.0f / 128.0f) - 1.0f - 0x1p-20f;
        int c = 0;
        #pragma unroll
        for (int k = 0; k < 31; ++k) c += (sBd[k] < nj) ? 1 : 0;
        lut[j] = (unsigned char)c;
    }
}

// ---------------- blockwise NF5 quantize: fp32 -> bf16 ----------------
// One thread = 8 consecutive elements; 4 lanes = one 32-element block.
__device__ __forceinline__ unsigned short q_one(float n, float scale,
                                                const float* sT, const float* sBnd,
                                                const unsigned char* sLut) {
    float u = fmaf(n, 0.5f, 0.5f);                 // [0,1]
    int b = (int)(u * 256.0f);
    b = min(b, 255);
    int base = sLut[b];
    int idx = base + ((sBnd[base] < n) ? 1 : 0);   // == count(bounds < n)
    float q = sT[idx] * scale;                     // exact fp32 (pow2 scale)
    __hip_bfloat16 h = __float2bfloat16(q);
    return *reinterpret_cast<unsigned short*>(&h);
}

__global__ __launch_bounds__(256) void quantize_k(const float4* __restrict__ in,
                                                  US8* __restrict__ out,
                                                  const float* __restrict__ table,
                                                  const float* __restrict__ bounds,
                                                  const unsigned char* __restrict__ lut,
                                                  int n8) {
    __shared__ float sT[32], sBnd[32];
    __shared__ unsigned char sLut[256];
    const int tid = threadIdx.x;
    if (tid < 32) { sT[tid] = table[tid]; sBnd[tid] = bounds[tid]; }
    sLut[tid] = lut[tid];
    __syncthreads();
    const int t = blockIdx.x * 256 + tid;
    if (t >= n8) return;
    float4 v0 = in[2 * t];
    float4 v1 = in[2 * t + 1];
    float am = fmaxf(fmaxf(fmaxf(fabsf(v0.x), fabsf(v0.y)), fmaxf(fabsf(v0.z), fabsf(v0.w))),
                     fmaxf(fmaxf(fabsf(v1.x), fabsf(v1.y)), fmaxf(fabsf(v1.z), fabsf(v1.w))));
    // reduce amax over the 4-lane group (32-element block)
    am = fmaxf(am, __shfl_xor(am, 1));
    am = fmaxf(am, __shfl_xor(am, 2));
    am = fmaxf(am, 1e-12f);
    // scale = exp2(ceil(log2(am))): smallest power of 2 >= am
    int e;
    float m = frexpf(am, &e);                      // am = m * 2^e, m in [0.5,1)
    int se = (m == 0.5f) ? (e - 1) : e;
    float scale = ldexpf(1.0f, se);
    float inv   = ldexpf(1.0f, -se);               // exact reciprocal
    US8 o;
    o.s[0] = q_one(v0.x * inv, scale, sT, sBnd, sLut);
    o.s[1] = q_one(v0.y * inv, scale, sT, sBnd, sLut);
    o.s[2] = q_one(v0.z * inv, scale, sT, sBnd, sLut);
    o.s[3] = q_one(v0.w * inv, scale, sT, sBnd, sLut);
    o.s[4] = q_one(v1.x * inv, scale, sT, sBnd, sLut);
    o.s[5] = q_one(v1.y * inv, scale, sT, sBnd, sLut);
    o.s[6] = q_one(v1.z * inv, scale, sT, sBnd, sLut);
    o.s[7] = q_one(v1.w * inv, scale, sT, sBnd, sLut);
    out[t] = o;
}

// ---------------- bf16 MFMA GEMM, C[M,N] = A[M,K] * B[N,K]^T + bias ----------------
__device__ __forceinline__ void gload_lds16(const unsigned short* g, unsigned short* s) {
    __builtin_amdgcn_global_load_lds(
        (const __attribute__((address_space(1))) unsigned int*)g,
        (__attribute__((address_space(3))) unsigned int*)s, 16, 0, 0);
}

__global__ __launch_bounds__(256) void gemm_bt_k(const unsigned short* __restrict__ A,
                                                 const unsigned short* __restrict__ B,
                                                 const float* __restrict__ bias,
                                                 float* __restrict__ C,
                                                 int M, int N, int K) {
    __shared__ unsigned short sA[128 * 64];
    __shared__ unsigned short sB[128 * 64];
    const int t = threadIdx.x;
    const int w = t >> 6, l = t & 63;

    // XCD-aware swizzle: round-robin dispatch sends lin%8 to XCD lin%8.
    // Map so each XCD walks all n-blocks of ONE m-stripe consecutively ->
    // A-stripe (256KB) stays hot in that XCD's 4MB L2.
    const int nB = N >> 7, mB = M >> 7;
    const unsigned int lin = blockIdx.x;
    int m_idx, n_idx;
    if ((mB & 7) == 0) {
        const unsigned int xcd = lin & 7, seq = lin >> 3;
        n_idx = seq % (unsigned int)nB;
        m_idx = (seq / (unsigned int)nB) * 8 + xcd;
    } else {
        n_idx = lin % (unsigned int)nB;
        m_idx = lin / (unsigned int)nB;
    }
    const int m_blk = m_idx * 128, n_blk = n_idx * 128;
    const int wm = (w >> 1) * 64, wn = (w & 1) * 64;   // wave's 64x64 quadrant

    f32x4 acc[4][4];
    #pragma unroll
    for (int i = 0; i < 4; ++i)
        #pragma unroll
        for (int j = 0; j < 4; ++j)
            acc[i][j] = (f32x4){0.f, 0.f, 0.f, 0.f};

    const int st_row = (l >> 3);        // 0..7 within an 8-row chunk
    const int st_col = (l & 7) * 8;     // 0..56, 8 halves each

    for (int kt = 0; kt < K; kt += 64) {
        __syncthreads();
        #pragma unroll
        for (int j = 0; j < 4; ++j) {
            const int chunk = w * 4 + j;             // 0..15 -> rows chunk*8..+7
            const int row = chunk * 8 + st_row;      // 0..127
            const unsigned short* ga = A + (size_t)(m_blk + row) * K + kt + st_col;
            const unsigned short* gb = B + (size_t)(n_blk + row) * K + kt + st_col;
            gload_lds16(ga, &sA[chunk * 512]);       // wave-uniform LDS base + lane*16B
            gload_lds16(gb, &sB[chunk * 512]);
        }
        __syncthreads();
        #pragma unroll
        for (int ks = 0; ks < 2; ++ks) {
            const int kof = ks * 32 + (l >> 4) * 8;  // A[m=l&15][k=quad*8+j] layout
            const int rsel = l & 15;
            short8 a[4], b[4];
            #pragma unroll
            for (int i = 0; i < 4; ++i) {
                a[i] = *(const short8*)&sA[(wm + i * 16 + rsel) * 64 + kof];
                b[i] = *(const short8*)&sB[(wn + i * 16 + rsel) * 64 + kof];
            }
            #pragma unroll
            for (int i = 0; i < 4; ++i)
                #pragma unroll
                for (int j = 0; j < 4; ++j)
                    acc[i][j] = __builtin_amdgcn_mfma_f32_16x16x32_bf16(
                        a[i], b[j], acc[i][j], 0, 0, 0);
        }
    }

    // epilogue: C/D layout col = l&15, row = (l>>4)*4 + r
    float bv[4];
    #pragma unroll
    for (int j = 0; j < 4; ++j) bv[j] = bias[n_blk + wn + j * 16 + (l & 15)];
    #pragma unroll
    for (int i = 0; i < 4; ++i) {
        #pragma unroll
        for (int r = 0; r < 4; ++r) {
            const int row = m_blk + wm + i * 16 + (l >> 4) * 4 + r;
            float* cp = C + (size_t)row * N + n_blk + wn + (l & 15);
            #pragma unroll
            for (int j = 0; j < 4; ++j)
                cp[j * 16] = acc[i][j][r] + bv[j];
        }
    }
}

extern "C" void kernel_launch(void* const* d_in, const int* in_sizes, int n_in,
                              void* d_out, int out_size, void* d_ws, size_t ws_size,
                              hipStream_t stream) {
    const float* x    = (const float*)d_in[0];
    const float* wgt  = (const float*)d_in[1];
    const float* bias = (const float*)d_in[2];
    float* out = (float*)d_out;

    const int x_size = in_sizes[0];      // 33554432
    const int w_size = in_sizes[1];      // 1048576
    const int N = in_sizes[2];           // 1024 (Dout)
    const int K = w_size / N;            // 1024 (Din)
    const int M = x_size / K;            // 32768

    char* ws = (char*)d_ws;
    unsigned short* qx = (unsigned short*)ws;
    unsigned short* qw = (unsigned short*)(ws + (size_t)M * K * sizeof(unsigned short));
    float* table  = (float*)(ws + (size_t)M * K * 2 + (size_t)N * K * 2);
    float* bounds = table + 32;
    unsigned char* lut = (unsigned char*)(bounds + 32);

    build_table_k<<<1, 32, 0, stream>>>(table, bounds, lut);

    const int n8x = x_size / 8;
    quantize_k<<<(n8x + 255) / 256, 256, 0, stream>>>(
        (const float4*)x, (US8*)qx, table, bounds, lut, n8x);
    const int n8w = w_size / 8;
    quantize_k<<<(n8w + 255) / 256, 256, 0, stream>>>(
        (const float4*)wgt, (US8*)qw, table, bounds, lut, n8w);

    const int grid = (M / 128) * (N / 128);   // 2048
    gemm_bt_k<<<grid, 256, 0, stream>>>(qx, qw, bias, out, M, N, K);
}

// Round 3
// 307.668 us; speedup vs baseline: 1.1003x; 1.0878x over previous
//
#include <hip/hip_runtime.h>
#include <hip/hip_bf16.h>

typedef __attribute__((ext_vector_type(8))) short short8;
typedef __attribute__((ext_vector_type(4))) float f32x4;

struct alignas(16) US8 { unsigned short s[8]; };

// ---------------- ndtri in double (Acklam + 2 Halley refinements) ----------------
__device__ double ndtri_d(double p) {
    const double a1 = -3.969683028665376e+01, a2 = 2.209460984245205e+02,
                 a3 = -2.759285104469687e+02, a4 = 1.383577518672690e+02,
                 a5 = -3.066479806614716e+01, a6 = 2.506628277459239e+00;
    const double b1 = -5.447609879822406e+01, b2 = 1.615858368580409e+02,
                 b3 = -1.556989798598866e+02, b4 = 6.680131188771972e+01,
                 b5 = -1.328068155288572e+01;
    const double c1 = -7.784894002430293e-03, c2 = -3.223964580411365e-01,
                 c3 = -2.400758277161838e+00, c4 = -2.549732539343734e+00,
                 c5 = 4.374664141464968e+00,  c6 = 2.938163982698783e+00;
    const double d1 = 7.784695709041462e-03, d2 = 3.224671290700398e-01,
                 d3 = 2.445134137142996e+00, d4 = 3.754408661907416e+00;
    const double plow = 0.02425, phigh = 1.0 - 0.02425;
    double x;
    if (p < plow) {
        double q = sqrt(-2.0 * log(p));
        x = (((((c1*q+c2)*q+c3)*q+c4)*q+c5)*q+c6) / ((((d1*q+d2)*q+d3)*q+d4)*q+1.0);
    } else if (p <= phigh) {
        double q = p - 0.5, r = q * q;
        x = (((((a1*r+a2)*r+a3)*r+a4)*r+a5)*r+a6)*q / (((((b1*r+b2)*r+b3)*r+b4)*r+b5)*r+1.0);
    } else {
        double q = sqrt(-2.0 * log(1.0 - p));
        x = -(((((c1*q+c2)*q+c3)*q+c4)*q+c5)*q+c6) / ((((d1*q+d2)*q+d3)*q+d4)*q+1.0);
    }
    #pragma unroll
    for (int it = 0; it < 2; ++it) {
        double e = 0.5 * erfc(-x * 0.70710678118654752440) - p;
        double u = e * 2.50662827463100050242 * exp(0.5 * x * x);
        x = x - u / (1.0 + 0.5 * x * u);
    }
    return x;
}

// table[32], bounds[32] (bounds[31]=+inf), lut[256] bucket->base index
__global__ void build_table_k(float* __restrict__ table, float* __restrict__ bounds,
                              unsigned char* __restrict__ lut) {
    __shared__ float sT[32], sBd[32];
    const int i = threadIdx.x;  // 0..31
    const double OFF = 0.9677083;
    double v;
    if (i == 16) {
        v = 0.0;
    } else if (i < 16) {
        const double a = 1.0 - OFF;
        double p = a + (0.5 - a) * ((double)i / 16.0);
        v = ndtri_d(p) / (-ndtri_d(a));
    } else {
        int j = i - 16;
        double p = 0.5 + (OFF - 0.5) * ((double)j / 15.0);
        v = ndtri_d(p) / ndtri_d(OFF);
    }
    float tv = (float)v;
    sT[i] = tv;
    table[i] = tv;
    __syncthreads();
    float bd;
    if (i < 31) bd = 0.5f * (sT[i] + sT[i + 1]);   // fp32, like reference
    else        bd = __builtin_inff();
    sBd[i] = bd;
    bounds[i] = bd;
    __syncthreads();
    // LUT with margin 2^-20: base[j] = count(bounds < n_j - margin).
    for (int j = i; j < 256; j += 32) {
        float nj = (float)j * (1.0f / 128.0f) - 1.0f - 0x1p-20f;
        int c = 0;
        #pragma unroll
        for (int k = 0; k < 31; ++k) c += (sBd[k] < nj) ? 1 : 0;
        lut[j] = (unsigned char)c;
    }
}

// ---------------- blockwise NF5 quantize: fp32 -> bf16 ----------------
// One thread = 8 consecutive elements; 4 lanes = one 32-element block.
// Handles BOTH x and w in a single launch (block ranges split).
__device__ __forceinline__ unsigned short q_one(float n, float scale,
                                                const float* sT, const float* sBnd,
                                                const unsigned char* sLut) {
    float u = fmaf(n, 0.5f, 0.5f);                 // [0,1]
    int b = (int)(u * 256.0f);
    b = min(b, 255);
    int base = sLut[b];
    int idx = base + ((sBnd[base] < n) ? 1 : 0);   // == count(bounds < n)
    float q = sT[idx] * scale;                     // exact fp32 (pow2 scale)
    __hip_bfloat16 h = __float2bfloat16(q);
    return *reinterpret_cast<unsigned short*>(&h);
}

__global__ __launch_bounds__(256) void quantize_k(const float4* __restrict__ x,
                                                  US8* __restrict__ qx, int nblk_x, int n8x,
                                                  const float4* __restrict__ wgt,
                                                  US8* __restrict__ qw, int n8w,
                                                  const float* __restrict__ table,
                                                  const float* __restrict__ bounds,
                                                  const unsigned char* __restrict__ lut) {
    __shared__ float sT[32], sBnd[32];
    __shared__ unsigned char sLut[256];
    const int tid = threadIdx.x;
    if (tid < 32) { sT[tid] = table[tid]; sBnd[tid] = bounds[tid]; }
    sLut[tid] = lut[tid];
    __syncthreads();
    const float4* in; US8* out; int t, n8;
    if ((int)blockIdx.x < nblk_x) { in = x;   out = qx; t = blockIdx.x * 256 + tid;            n8 = n8x; }
    else                          { in = wgt; out = qw; t = (blockIdx.x - nblk_x) * 256 + tid; n8 = n8w; }
    if (t >= n8) return;
    float4 v0 = in[2 * t];
    float4 v1 = in[2 * t + 1];
    float am = fmaxf(fmaxf(fmaxf(fabsf(v0.x), fabsf(v0.y)), fmaxf(fabsf(v0.z), fabsf(v0.w))),
                     fmaxf(fmaxf(fabsf(v1.x), fabsf(v1.y)), fmaxf(fabsf(v1.z), fabsf(v1.w))));
    am = fmaxf(am, __shfl_xor(am, 1));
    am = fmaxf(am, __shfl_xor(am, 2));
    am = fmaxf(am, 1e-12f);
    int e;
    float m = frexpf(am, &e);                      // am = m * 2^e, m in [0.5,1)
    int se = (m == 0.5f) ? (e - 1) : e;
    float scale = ldexpf(1.0f, se);
    float inv   = ldexpf(1.0f, -se);               // exact reciprocal
    US8 o;
    o.s[0] = q_one(v0.x * inv, scale, sT, sBnd, sLut);
    o.s[1] = q_one(v0.y * inv, scale, sT, sBnd, sLut);
    o.s[2] = q_one(v0.z * inv, scale, sT, sBnd, sLut);
    o.s[3] = q_one(v0.w * inv, scale, sT, sBnd, sLut);
    o.s[4] = q_one(v1.x * inv, scale, sT, sBnd, sLut);
    o.s[5] = q_one(v1.y * inv, scale, sT, sBnd, sLut);
    o.s[6] = q_one(v1.z * inv, scale, sT, sBnd, sLut);
    o.s[7] = q_one(v1.w * inv, scale, sT, sBnd, sLut);
    out[t] = o;
}

// ---------------- bf16 MFMA GEMM, C[M,N] = A[M,K] * B[N,K]^T + bias ----------------
// XOR-swizzled LDS layout: within an 8-row chunk, LDS 16B-slot (r8, u) holds
// k-octet k8 = u ^ r8 of row r8. Staging lane l (slot r8=l>>3, u=l&7) therefore
// fetches global k-octet (l&7)^(l>>3) -> same 128B row segment, still coalesced.
// Fragment reads at fixed k8 then hit all 8 bank-quads across r8 -> conflict-free.
__device__ __forceinline__ void gload_lds16(const unsigned short* g, unsigned short* s) {
    __builtin_amdgcn_global_load_lds(
        (const __attribute__((address_space(1))) unsigned int*)g,
        (__attribute__((address_space(3))) unsigned int*)s, 16, 0, 0);
}

__global__ __launch_bounds__(256) void gemm_bt_k(const unsigned short* __restrict__ A,
                                                 const unsigned short* __restrict__ B,
                                                 const float* __restrict__ bias,
                                                 float* __restrict__ C,
                                                 int M, int N, int K) {
    __shared__ unsigned short sA[2][128 * 64];
    __shared__ unsigned short sB[2][128 * 64];
    const int t = threadIdx.x;
    const int w = t >> 6, l = t & 63;

    // XCD-aware swizzle: each XCD walks all n-blocks of ONE m-stripe.
    const int nB = N >> 7, mB = M >> 7;
    const unsigned int lin = blockIdx.x;
    int m_idx, n_idx;
    if ((mB & 7) == 0) {
        const unsigned int xcd = lin & 7, seq = lin >> 3;
        n_idx = seq % (unsigned int)nB;
        m_idx = (seq / (unsigned int)nB) * 8 + xcd;
    } else {
        n_idx = lin % (unsigned int)nB;
        m_idx = lin / (unsigned int)nB;
    }
    const int m_blk = m_idx * 128, n_blk = n_idx * 128;
    const int wm = (w >> 1) * 64, wn = (w & 1) * 64;   // wave's 64x64 quadrant

    f32x4 acc[4][4];
    #pragma unroll
    for (int i = 0; i < 4; ++i)
        #pragma unroll
        for (int j = 0; j < 4; ++j)
            acc[i][j] = (f32x4){0.f, 0.f, 0.f, 0.f};

    const int st_row = l >> 3;                   // r8 within chunk
    const int st_col = ((l & 7) ^ st_row) * 8;   // swizzled k-octet (halves)

    const int kIters = K >> 6;

    // ---- stage helper (macro-ish lambda), wave-uniform LDS base ----
    auto stage = [&](int buf, int kt) {
        #pragma unroll
        for (int j = 0; j < 4; ++j) {
            const int chunk = w * 4 + j;                 // rows chunk*8..+7
            const int row = chunk * 8 + st_row;
            const unsigned short* ga = A + (size_t)(m_blk + row) * K + kt + st_col;
            const unsigned short* gb = B + (size_t)(n_blk + row) * K + kt + st_col;
            gload_lds16(ga, &sA[buf][chunk * 512]);
            gload_lds16(gb, &sB[buf][chunk * 512]);
        }
    };

    stage(0, 0);   // prologue

    const int rsel = l & 15;
    const int quad = l >> 4;                 // 0..3
    for (int it = 0; it < kIters; ++it) {
        __syncthreads();                     // drains stage(buf) issued last iter
        const int buf = it & 1;
        if (it + 1 < kIters) stage(buf ^ 1, (it + 1) * 64);
        #pragma unroll
        for (int ks = 0; ks < 2; ++ks) {
            const int k8 = ks * 4 + quad;    // k-octet index 0..7
            short8 a[4], b[4];
            #pragma unroll
            for (int i = 0; i < 4; ++i) {
                const int ra = wm + i * 16 + rsel;
                const int ua = (ra >> 3) * 64 + (ra & 7) * 8 + ((k8 ^ (ra & 7)) & 7);
                a[i] = *(const short8*)&sA[buf][ua * 8];
                const int rb = wn + i * 16 + rsel;
                const int ub = (rb >> 3) * 64 + (rb & 7) * 8 + ((k8 ^ (rb & 7)) & 7);
                b[i] = *(const short8*)&sB[buf][ub * 8];
            }
            #pragma unroll
            for (int i = 0; i < 4; ++i)
                #pragma unroll
                for (int j = 0; j < 4; ++j)
                    acc[i][j] = __builtin_amdgcn_mfma_f32_16x16x32_bf16(
                        a[i], b[j], acc[i][j], 0, 0, 0);
        }
    }

    // epilogue: C/D layout col = l&15, row = (l>>4)*4 + r
    float bv[4];
    #pragma unroll
    for (int j = 0; j < 4; ++j) bv[j] = bias[n_blk + wn + j * 16 + (l & 15)];
    #pragma unroll
    for (int i = 0; i < 4; ++i) {
        #pragma unroll
        for (int r = 0; r < 4; ++r) {
            const int row = m_blk + wm + i * 16 + (l >> 4) * 4 + r;
            float* cp = C + (size_t)row * N + n_blk + wn + (l & 15);
            #pragma unroll
            for (int j = 0; j < 4; ++j)
                cp[j * 16] = acc[i][j][r] + bv[j];
        }
    }
}

extern "C" void kernel_launch(void* const* d_in, const int* in_sizes, int n_in,
                              void* d_out, int out_size, void* d_ws, size_t ws_size,
                              hipStream_t stream) {
    const float* x    = (const float*)d_in[0];
    const float* wgt  = (const float*)d_in[1];
    const float* bias = (const float*)d_in[2];
    float* out = (float*)d_out;

    const int x_size = in_sizes[0];      // 33554432
    const int w_size = in_sizes[1];      // 1048576
    const int N = in_sizes[2];           // 1024 (Dout)
    const int K = w_size / N;            // 1024 (Din)
    const int M = x_size / K;            // 32768

    char* ws = (char*)d_ws;
    unsigned short* qx = (unsigned short*)ws;
    unsigned short* qw = (unsigned short*)(ws + (size_t)M * K * sizeof(unsigned short));
    float* table  = (float*)(ws + (size_t)M * K * 2 + (size_t)N * K * 2);
    float* bounds = table + 32;
    unsigned char* lut = (unsigned char*)(bounds + 32);

    build_table_k<<<1, 32, 0, stream>>>(table, bounds, lut);

    const int n8x = x_size / 8, n8w = w_size / 8;
    const int nblk_x = (n8x + 255) / 256, nblk_w = (n8w + 255) / 256;
    quantize_k<<<nblk_x + nblk_w, 256, 0, stream>>>(
        (const float4*)x, (US8*)qx, nblk_x, n8x,
        (const float4*)wgt, (US8*)qw, n8w, table, bounds, lut);

    const int grid = (M / 128) * (N / 128);   // 2048
    gemm_bt_k<<<grid, 256, 0, stream>>>(qx, qw, bias, out, M, N, K);
}